// Round 1
// baseline (208.422 us; speedup 1.0000x reference)
//
#include <hip/hip_runtime.h>
#include <cfloat>
#include <cmath>

#define BB 128
#define MM 50
#define AA 2100
#define NC 30
#define DCH 64
#define CHT 94   // total channels = 64 + 30

__device__ __forceinline__ float softplus_f(float x) {
    // log(1+exp(x)), stable
    return fmaxf(x, 0.0f) + log1pf(expf(-fabsf(x)));
}

// One wave (64 lanes) per (b,m) pair: argmin over 2100 anchors, then scatter
// class-bit + fg-bit into mask[b*AA + best].
__global__ void assign_kernel(const float* __restrict__ txy,
                              const int* __restrict__ tcls,
                              const unsigned char* __restrict__ valid,
                              const float* __restrict__ anchors,
                              unsigned int* __restrict__ mask) {
    int gtid = blockIdx.x * blockDim.x + threadIdx.x;
    int pair = gtid >> 6;
    int lane = gtid & 63;
    if (pair >= BB * MM) return;
    if (!valid[pair]) return;   // invalid targets scatter nothing (max with 0/false)

    float cx = txy[pair * 2 + 0] * 320.0f;
    float cy = txy[pair * 2 + 1] * 320.0f;

    float bd = FLT_MAX;
    int   bi = 0x7fffffff;
    for (int a = lane; a < AA; a += 64) {
        float dx = anchors[2 * a]     - cx;
        float dy = anchors[2 * a + 1] - cy;
        float d = sqrtf(dx * dx + dy * dy);   // match jnp.linalg.norm (f32 sqrt)
        if (d < bd) { bd = d; bi = a; }       // strict < keeps lowest index
    }
    // butterfly reduce, tie-break on lowest anchor index (jnp.argmin semantics)
    for (int off = 32; off > 0; off >>= 1) {
        float od = __shfl_xor(bd, off);
        int   oi = __shfl_xor(bi, off);
        if (od < bd || (od == bd && oi < bi)) { bd = od; bi = oi; }
    }
    if (lane == 0) {
        int b = pair / MM;
        int c = tcls[pair];
        atomicOr(&mask[b * AA + bi], (1u << c) | 0x80000000u);
    }
}

// One thread per (b,a). BCE over 30 class channels; huber(mean of 64 dist
// channels) only where fg. Block-reduce into f64 atomics.
__global__ __launch_bounds__(256)
void loss_kernel(const float* __restrict__ pred,
                 const unsigned int* __restrict__ mask,
                 double* __restrict__ sums,        // [0]=cls numerator, [1]=box numerator
                 unsigned int* __restrict__ cnt) {
    int idx = blockIdx.x * blockDim.x + threadIdx.x;   // b*AA + a
    double local_cls = 0.0;
    double local_box = 0.0;
    unsigned int local_fg = 0;

    if (idx < BB * AA) {
        int b = idx / AA;
        int a = idx - b * AA;
        const float* pb = pred + (size_t)b * CHT * AA + a;
        unsigned int mw = mask[idx];

        // classification: t=1 -> softplus(-x), t=0 -> softplus(x)
        #pragma unroll
        for (int c = 0; c < NC; ++c) {
            float x = pb[(size_t)(DCH + c) * AA];
            float sp = (mw & (1u << c)) ? softplus_f(-x) : softplus_f(x);
            local_cls += (double)sp;
        }

        // box: only fg anchors contribute
        if (mw & 0x80000000u) {
            float s = 0.0f;
            #pragma unroll
            for (int ch = 0; ch < DCH; ++ch) s += pb[(size_t)ch * AA];
            float m = s * (1.0f / 64.0f);
            float e = m - 1.0f;
            float ae = fabsf(e);
            float huber = (ae <= 1.0f) ? 0.5f * e * e : ae - 0.5f;
            local_box = (double)huber;
            local_fg = 1;
        }
    }

    // wave reduce
    for (int off = 32; off > 0; off >>= 1) {
        local_cls += __shfl_down(local_cls, off);
        local_box += __shfl_down(local_box, off);
        local_fg  += __shfl_down(local_fg, off);
    }
    __shared__ double s_cls[4];
    __shared__ double s_box[4];
    __shared__ unsigned int s_fg[4];
    int lane = threadIdx.x & 63;
    int w    = threadIdx.x >> 6;
    if (lane == 0) { s_cls[w] = local_cls; s_box[w] = local_box; s_fg[w] = local_fg; }
    __syncthreads();
    if (threadIdx.x == 0) {
        double tc = s_cls[0] + s_cls[1] + s_cls[2] + s_cls[3];
        double tb = s_box[0] + s_box[1] + s_box[2] + s_box[3];
        unsigned int tf = s_fg[0] + s_fg[1] + s_fg[2] + s_fg[3];
        atomicAdd(&sums[0], tc);
        atomicAdd(&sums[1], tb);
        if (tf) atomicAdd(cnt, tf);
    }
}

__global__ void finalize_kernel(const double* __restrict__ sums,
                                const unsigned int* __restrict__ cnt,
                                float* __restrict__ out) {
    double sum_cls = sums[0];
    double sum_box = sums[1];
    unsigned int c = *cnt;
    out[0] = (c > 0) ? (float)(sum_box / (double)c) : 0.0f;          // loss_box
    out[1] = (float)(sum_cls / (double)((size_t)BB * NC * AA));      // loss_cls
}

extern "C" void kernel_launch(void* const* d_in, const int* in_sizes, int n_in,
                              void* d_out, int out_size, void* d_ws, size_t ws_size,
                              hipStream_t stream) {
    const float*         pred    = (const float*)d_in[0];
    const int*           tcls    = (const int*)d_in[1];
    const float*         txy     = (const float*)d_in[2];
    const unsigned char* valid   = (const unsigned char*)d_in[3];  // numpy bool, 1 byte
    const float*         anchors = (const float*)d_in[4];

    float* out = (float*)d_out;

    // workspace layout
    const size_t MASK_BYTES = (size_t)BB * AA * sizeof(unsigned int);  // 1,075,200
    unsigned int* mask = (unsigned int*)d_ws;
    double*       sums = (double*)((char*)d_ws + MASK_BYTES);          // [0],[1]
    unsigned int* cnt  = (unsigned int*)((char*)d_ws + MASK_BYTES + 2 * sizeof(double));

    // zero mask + accumulators (ws is poisoned to 0xAA before every launch)
    hipMemsetAsync(d_ws, 0, MASK_BYTES + 2 * sizeof(double) + sizeof(unsigned int), stream);

    // assignment: one wave per (b,m)
    {
        int waves = BB * MM;                 // 6400
        int threads = waves * 64;            // 409600
        int block = 256;
        int grid = (threads + block - 1) / block;  // 1600
        assign_kernel<<<grid, block, 0, stream>>>(txy, tcls, valid, anchors, mask);
    }

    // main loss: one thread per (b,a)
    {
        int total = BB * AA;                 // 268800
        int block = 256;
        int grid = (total + block - 1) / block;    // 1050
        loss_kernel<<<grid, block, 0, stream>>>(pred, mask, sums, cnt);
    }

    finalize_kernel<<<1, 1, 0, stream>>>(sums, cnt, out);
}

// Round 2
// 176.165 us; speedup vs baseline: 1.1831x; 1.1831x over previous
//
#include <hip/hip_runtime.h>
#include <cfloat>
#include <cmath>

#define BB 128
#define MM 50
#define AA 2100
#define NC 30
#define DCH 64
#define CHT 94   // total channels = 64 + 30

// One wave (64 lanes) per (b,m) pair: argmin over 2100 anchors (squared
// distance — argmin-invariant), then scatter class-bit + fg-bit.
__global__ void assign_kernel(const float* __restrict__ txy,
                              const int* __restrict__ tcls,
                              const unsigned char* __restrict__ valid,
                              const float* __restrict__ anchors,
                              unsigned int* __restrict__ mask) {
    int gtid = blockIdx.x * blockDim.x + threadIdx.x;
    int pair = gtid >> 6;
    int lane = gtid & 63;
    if (pair >= BB * MM) return;
    if (!valid[pair]) return;   // invalid targets scatter nothing

    float cx = txy[pair * 2 + 0] * 320.0f;
    float cy = txy[pair * 2 + 1] * 320.0f;

    const float2* __restrict__ anc = (const float2*)anchors;
    float bd = FLT_MAX;
    int   bi = 0x7fffffff;
    #pragma unroll 4
    for (int a = lane; a < AA; a += 64) {
        float2 p = anc[a];
        float dx = p.x - cx;
        float dy = p.y - cy;
        float d = dx * dx + dy * dy;          // squared dist: same argmin
        if (d < bd) { bd = d; bi = a; }       // strict < keeps lowest index
    }
    // butterfly reduce, tie-break on lowest anchor index
    for (int off = 32; off > 0; off >>= 1) {
        float od = __shfl_xor(bd, off);
        int   oi = __shfl_xor(bi, off);
        if (od < bd || (od == bd && oi < bi)) { bd = od; bi = oi; }
    }
    if (lane == 0) {
        int b = pair / MM;
        int c = tcls[pair];
        atomicOr(&mask[b * AA + bi], (1u << c) | 0x80000000u);
    }
}

// One thread per (b,a). Prefetch all 30 class logits into registers (loads
// pipelined), then one softplus each: softplus(-x) = softplus(x) - x, so the
// target bit only adds a subtract. Box huber only at fg anchors (~1% of
// threads). f32 per-block reduce, f64 atomics across blocks.
__global__ __launch_bounds__(256)
void loss_kernel(const float* __restrict__ pred,
                 const unsigned int* __restrict__ mask,
                 double* __restrict__ sums,        // [0]=cls num, [1]=box num
                 unsigned int* __restrict__ cnt) {
    int idx = blockIdx.x * blockDim.x + threadIdx.x;   // b*AA + a
    float acc_cls = 0.0f;
    float box = 0.0f;
    int is_fg = 0;

    if (idx < BB * AA) {
        int b = idx / AA;
        int a = idx - b * AA;
        const float* __restrict__ pc = pred + (size_t)b * CHT * AA
                                            + (size_t)DCH * AA + a;
        unsigned int mw = mask[idx];

        float x[NC];
        #pragma unroll
        for (int c = 0; c < NC; ++c) x[c] = pc[(size_t)c * AA];   // 30 loads in flight

        #pragma unroll
        for (int c = 0; c < NC; ++c) {
            float v = x[c];
            // softplus(v) = max(v,0) + log(1+exp(-|v|)); hw exp/log
            float sp = fmaxf(v, 0.0f) + __logf(1.0f + __expf(-fabsf(v)));
            acc_cls += sp - (((mw >> c) & 1u) ? v : 0.0f);  // bit set -> softplus(-v)
        }

        if (mw & 0x80000000u) {
            const float* __restrict__ pd = pred + (size_t)b * CHT * AA + a;
            float s = 0.0f;
            #pragma unroll 16
            for (int ch = 0; ch < DCH; ++ch) s += pd[(size_t)ch * AA];
            float m = s * (1.0f / 64.0f);
            float e = m - 1.0f;
            float ae = fabsf(e);
            box = (ae <= 1.0f) ? 0.5f * e * e : ae - 0.5f;
            is_fg = 1;
        }
    }

    // wave reduce (f32)
    for (int off = 32; off > 0; off >>= 1) {
        acc_cls += __shfl_down(acc_cls, off);
        box     += __shfl_down(box, off);
    }
    unsigned long long bal = __ballot(is_fg);

    __shared__ float s_cls[4];
    __shared__ float s_box[4];
    __shared__ unsigned int s_fg[4];
    int lane = threadIdx.x & 63;
    int w    = threadIdx.x >> 6;
    if (lane == 0) {
        s_cls[w] = acc_cls;
        s_box[w] = box;
        s_fg[w]  = (unsigned int)__popcll(bal);
    }
    __syncthreads();
    if (threadIdx.x == 0) {
        double tc = (double)s_cls[0] + s_cls[1] + s_cls[2] + s_cls[3];
        double tb = (double)s_box[0] + s_box[1] + s_box[2] + s_box[3];
        unsigned int tf = s_fg[0] + s_fg[1] + s_fg[2] + s_fg[3];
        atomicAdd(&sums[0], tc);
        atomicAdd(&sums[1], tb);
        if (tf) atomicAdd(cnt, tf);
    }
}

__global__ void finalize_kernel(const double* __restrict__ sums,
                                const unsigned int* __restrict__ cnt,
                                float* __restrict__ out) {
    double sum_cls = sums[0];
    double sum_box = sums[1];
    unsigned int c = *cnt;
    out[0] = (c > 0) ? (float)(sum_box / (double)c) : 0.0f;          // loss_box
    out[1] = (float)(sum_cls / (double)((size_t)BB * NC * AA));      // loss_cls
}

extern "C" void kernel_launch(void* const* d_in, const int* in_sizes, int n_in,
                              void* d_out, int out_size, void* d_ws, size_t ws_size,
                              hipStream_t stream) {
    const float*         pred    = (const float*)d_in[0];
    const int*           tcls    = (const int*)d_in[1];
    const float*         txy     = (const float*)d_in[2];
    const unsigned char* valid   = (const unsigned char*)d_in[3];  // numpy bool
    const float*         anchors = (const float*)d_in[4];

    float* out = (float*)d_out;

    const size_t MASK_BYTES = (size_t)BB * AA * sizeof(unsigned int);
    unsigned int* mask = (unsigned int*)d_ws;
    double*       sums = (double*)((char*)d_ws + MASK_BYTES);
    unsigned int* cnt  = (unsigned int*)((char*)d_ws + MASK_BYTES + 2 * sizeof(double));

    hipMemsetAsync(d_ws, 0, MASK_BYTES + 2 * sizeof(double) + sizeof(unsigned int), stream);

    {   // assignment: one wave per (b,m)
        int threads = BB * MM * 64;
        int block = 256;
        int grid = (threads + block - 1) / block;
        assign_kernel<<<grid, block, 0, stream>>>(txy, tcls, valid, anchors, mask);
    }
    {   // main loss: one thread per (b,a)
        int total = BB * AA;
        int block = 256;
        int grid = (total + block - 1) / block;
        loss_kernel<<<grid, block, 0, stream>>>(pred, mask, sums, cnt);
    }
    finalize_kernel<<<1, 1, 0, stream>>>(sums, cnt, out);
}